// Round 1
// 214.413 us; speedup vs baseline: 1.0272x; 1.0272x over previous
//
#include <hip/hip_runtime.h>

// ---------------------------------------------------------------------------
// Fused LeNet forward, round 9: occupancy-quantization fix.
//  - Round-8 counters: VALUBusy 39%, HBM 3%, Occupancy 26.7% = 8.5 waves/CU.
//    Grid 1024 = 4 blocks/CU of work but LDS 47.6KB -> only 3 resident:
//    full round of 3 + straggler round of 1 => half the time at 1/3 width.
//  - Fix: per-image LDS stride 1120 -> 720 floats:
//      * xs staged as 15 rows x 16 cols (4 float4/row; conv1 needs cols 0..14)
//        -> 720 fl, and each staged row is exactly one 64B cache line.
//      * p2 (400 fl) overwrites p1's head instead of living after it. Safe:
//        every p2 store depends on ALL p1 reads of this wave's images via the
//        accumulator chain, and no other wave touches this image's region.
//    LDS = 2852 + 8*720 = 8612 fl = 34.4 KB -> 4 blocks/CU, grid 1024 = one
//    clean round at 16 waves/CU.
//  - launch_bounds(256,4) caps VGPR at 128; measured use 84 (no spill risk).
//  - Everything else (ILP-2 per wave, reduced-extent convs, fc structure)
//    unchanged from round 8.
// ---------------------------------------------------------------------------

typedef float v2f __attribute__((ext_vector_type(2)));
__device__ __forceinline__ v2f mk2(float a, float b) { v2f t; t.x = a; t.y = b; return t; }
__device__ __forceinline__ v2f shfl2(v2f v, int src) {
    v2f r; r.x = __shfl(v.x, src, 64); r.y = __shfl(v.y, src, 64); return r;
}

constexpr int THREADS = 256;
constexpr int IPB = 8;                 // images per block (2 per wave)

// LDS layout (float offsets)
constexpr int W1P_OFF = 0;             // conv1 w packed [ocp0..2][k0..74][2] = 450
constexpr int W2P_OFF = 452;           // conv2 w packed [ocp0..7][k0..149][2] = 2400
constexpr int IMG_BASE = 2852;
// per-image offsets (region reused phase to phase):
constexpr int XS_OFF = 0;              // [3][15][16] = 720
constexpr int P1_OFF = 0;              // [6][10][12] = 720 (overwrites xs)
constexpr int P2_OFF = 0;              // [400] (overwrites p1 head; see header)
constexpr int F1_OFF = 0;              // [120] (p2 dead after fc1 partials)
constexpr int F2_OFF = 128;            // [84]
constexpr int IMG_STRIDE = 720;
constexpr int LDS_FLOATS = IMG_BASE + IPB * IMG_STRIDE;   // 8612 -> 34448 B

__device__ __forceinline__ void wave_sync() {
    asm volatile("s_waitcnt lgkmcnt(0)" ::: "memory");
}

extern "C" __global__ __launch_bounds__(THREADS, 4)
void lenet_fused(const float* __restrict__ x,
                 const float* __restrict__ w1,
                 const float* __restrict__ w2,
                 const float* __restrict__ fc1w, const float* __restrict__ fc1b,
                 const float* __restrict__ fc2w, const float* __restrict__ fc2b,
                 const float* __restrict__ fc3w, const float* __restrict__ fc3b,
                 float* __restrict__ out)
{
    __shared__ __align__(16) float lds[LDS_FLOATS];
    const int tid  = threadIdx.x;
    const int lane = tid & 63;
    const int wv   = tid >> 6;
    const int img0 = blockIdx.x * IPB;
    const v2f zero2 = mk2(0.f, 0.f);

    // ---- stage weights, repacked oc-pair-minor (block-wide) ----
    for (int i = tid; i < 450; i += THREADS) {
        int ocp = i / 150, rem = i - ocp * 150, k = rem >> 1, h = rem & 1;
        lds[W1P_OFF + i] = w1[(2 * ocp + h) * 75 + k];
    }
    for (int i = tid; i < 2400; i += THREADS) {
        int ocp = i / 300, rem = i - ocp * 300, k = rem >> 1, h = rem & 1;
        lds[W2P_OFF + i] = w2[(2 * ocp + h) * 150 + k];
    }

    // ---- stage input patches rows 0..14, cols 0..15 (2 images per wave) ----
    float* baseA = lds + IMG_BASE + (wv * 2) * IMG_STRIDE;
    float* baseB = baseA + IMG_STRIDE;
    {
        const float4* xgA = (const float4*)(x + (size_t)(img0 + wv * 2) * 3072);
        const float4* xgB = (const float4*)(x + (size_t)(img0 + wv * 2 + 1) * 3072);
        float4* dA = (float4*)(baseA + XS_OFF);
        float4* dB = (float4*)(baseB + XS_OFF);
        for (int i = lane; i < 180; i += 64) {       // 3ch * 15r * 4(f4)
            int c = i / 60, rem = i - c * 60;
            int r = rem >> 2, c4 = rem & 3;
            int src = c * 256 + r * 8 + c4;
            dA[i] = xgA[src];
            dB[i] = xgB[src];
        }
    }
    __syncthreads();   // weights + staging visible

    float* p1A = baseA + P1_OFF;
    float* p1B = baseB + P1_OFF;

    // ---- conv1 + relu + pool1 -> p1 [6][10][12], both images ----
    // lane -> (ocp 0..2, r 0..10); 33 active, dup lanes guarded at store.
    {
        const int l   = (lane < 33) ? lane : 32;
        const int ocp = l / 11;
        const int r   = l - ocp * 11;
        const float4* xsA = (const float4*)(baseA + XS_OFF);
        const float4* xsB = (const float4*)(baseB + XS_OFF);
        const v2f* w1p = (const v2f*)(lds + W1P_OFF);

        v2f accA[11], accB[11];
        #pragma unroll
        for (int c = 0; c < 11; ++c) { accA[c] = zero2; accB[c] = zero2; }

        #pragma unroll
        for (int i = 0; i < 15; ++i) {
            const int ci = i / 5, kr = i - ci * 5;
            const int b = ci * 60 + (r + kr) * 4;    // 16-col rows: 4 f4/row
            float4 A0 = xsA[b], A1 = xsA[b + 1], A2 = xsA[b + 2], A3 = xsA[b + 3];
            float4 B0 = xsB[b], B1 = xsB[b + 1], B2 = xsB[b + 2], B3 = xsB[b + 3];
            v2f W[5];
            #pragma unroll
            for (int kc = 0; kc < 5; ++kc) W[kc] = w1p[ocp * 75 + i * 5 + kc];
            float xa[16], xb[16];
            xa[0]=A0.x; xa[1]=A0.y; xa[2]=A0.z;  xa[3]=A0.w;
            xa[4]=A1.x; xa[5]=A1.y; xa[6]=A1.z;  xa[7]=A1.w;
            xa[8]=A2.x; xa[9]=A2.y; xa[10]=A2.z; xa[11]=A2.w;
            xa[12]=A3.x; xa[13]=A3.y; xa[14]=A3.z; xa[15]=A3.w;
            xb[0]=B0.x; xb[1]=B0.y; xb[2]=B0.z;  xb[3]=B0.w;
            xb[4]=B1.x; xb[5]=B1.y; xb[6]=B1.z;  xb[7]=B1.w;
            xb[8]=B2.x; xb[9]=B2.y; xb[10]=B2.z; xb[11]=B2.w;
            xb[12]=B3.x; xb[13]=B3.y; xb[14]=B3.z; xb[15]=B3.w;
            #pragma unroll
            for (int kc = 0; kc < 5; ++kc) {
                #pragma unroll
                for (int c = 0; c < 11; ++c) {
                    accA[c] = __builtin_elementwise_fma(
                        mk2(xa[c + kc], xa[c + kc]), W[kc], accA[c]);
                    accB[c] = __builtin_elementwise_fma(
                        mk2(xb[c + kc], xb[c + kc]), W[kc], accB[c]);
                }
            }
        }

        // relu + 2x2 stride-1 pool (packed over oc pair), both images
        v2f pmA[10], pmB[10], mA[10], mB[10];
        #pragma unroll
        for (int c = 0; c < 10; ++c) {
            v2f aA0 = __builtin_elementwise_max(accA[c], zero2);
            v2f aA1 = __builtin_elementwise_max(accA[c + 1], zero2);
            pmA[c] = __builtin_elementwise_max(aA0, aA1);
            v2f aB0 = __builtin_elementwise_max(accB[c], zero2);
            v2f aB1 = __builtin_elementwise_max(accB[c + 1], zero2);
            pmB[c] = __builtin_elementwise_max(aB0, aB1);
        }
        #pragma unroll
        for (int c = 0; c < 10; ++c) {
            mA[c] = __builtin_elementwise_max(pmA[c], shfl2(pmA[c], lane + 1));
            mB[c] = __builtin_elementwise_max(pmB[c], shfl2(pmB[c], lane + 1));
        }
        wave_sync();   // xs reads drained before overwriting region with p1
        if (r < 10) {
            const int oc0 = ocp * 2;
            float2* dA0 = (float2*)(p1A + oc0 * 120 + r * 12);
            float2* dA1 = (float2*)(p1A + (oc0 + 1) * 120 + r * 12);
            float2* dB0 = (float2*)(p1B + oc0 * 120 + r * 12);
            float2* dB1 = (float2*)(p1B + (oc0 + 1) * 120 + r * 12);
            #pragma unroll
            for (int j = 0; j < 5; ++j) {
                dA0[j] = make_float2(mA[2 * j].x, mA[2 * j + 1].x);
                dA1[j] = make_float2(mA[2 * j].y, mA[2 * j + 1].y);
                dB0[j] = make_float2(mB[2 * j].x, mB[2 * j + 1].x);
                dB1[j] = make_float2(mB[2 * j].y, mB[2 * j + 1].y);
            }
        }
    }
    wave_sync();

    // ---- conv2 + relu + pool2 -> p2 [16*5*5] flatten order, both images ----
    float* p2A = baseA + P2_OFF;
    float* p2B = baseB + P2_OFF;
    {
        const int l   = (lane < 48) ? lane : 47;
        const int ocp = l / 6;
        const int r   = l - ocp * 6;
        const float4* pA4 = (const float4*)p1A;
        const float2* pA2 = (const float2*)p1A;
        const float4* pB4 = (const float4*)p1B;
        const float2* pB2 = (const float2*)p1B;
        const v2f* w2p = (const v2f*)(lds + W2P_OFF);

        v2f accA[6], accB[6];
        #pragma unroll
        for (int c = 0; c < 6; ++c) { accA[c] = zero2; accB[c] = zero2; }

        #pragma unroll
        for (int i = 0; i < 30; ++i) {
            const int ci = i / 5, kr = i - ci * 5;
            float4 A0 = pA4[ci * 30 + (r + kr) * 3 + 0];
            float4 A1 = pA4[ci * 30 + (r + kr) * 3 + 1];
            float2 A2 = pA2[ci * 60 + (r + kr) * 6 + 4];
            float4 B0 = pB4[ci * 30 + (r + kr) * 3 + 0];
            float4 B1 = pB4[ci * 30 + (r + kr) * 3 + 1];
            float2 B2 = pB2[ci * 60 + (r + kr) * 6 + 4];
            v2f W[5];
            #pragma unroll
            for (int kc = 0; kc < 5; ++kc) W[kc] = w2p[ocp * 150 + i * 5 + kc];
            float xa[10], xb[10];
            xa[0]=A0.x; xa[1]=A0.y; xa[2]=A0.z; xa[3]=A0.w;
            xa[4]=A1.x; xa[5]=A1.y; xa[6]=A1.z; xa[7]=A1.w;
            xa[8]=A2.x; xa[9]=A2.y;
            xb[0]=B0.x; xb[1]=B0.y; xb[2]=B0.z; xb[3]=B0.w;
            xb[4]=B1.x; xb[5]=B1.y; xb[6]=B1.z; xb[7]=B1.w;
            xb[8]=B2.x; xb[9]=B2.y;
            #pragma unroll
            for (int kc = 0; kc < 5; ++kc) {
                #pragma unroll
                for (int c = 0; c < 6; ++c) {
                    accA[c] = __builtin_elementwise_fma(
                        mk2(xa[c + kc], xa[c + kc]), W[kc], accA[c]);
                    accB[c] = __builtin_elementwise_fma(
                        mk2(xb[c + kc], xb[c + kc]), W[kc], accB[c]);
                }
            }
        }

        v2f pmA[5], pmB[5], mA[5], mB[5];
        #pragma unroll
        for (int c = 0; c < 5; ++c) {
            v2f aA0 = __builtin_elementwise_max(accA[c], zero2);
            v2f aA1 = __builtin_elementwise_max(accA[c + 1], zero2);
            pmA[c] = __builtin_elementwise_max(aA0, aA1);
            v2f aB0 = __builtin_elementwise_max(accB[c], zero2);
            v2f aB1 = __builtin_elementwise_max(accB[c + 1], zero2);
            pmB[c] = __builtin_elementwise_max(aB0, aB1);
        }
        #pragma unroll
        for (int c = 0; c < 5; ++c) {
            mA[c] = __builtin_elementwise_max(pmA[c], shfl2(pmA[c], lane + 1));
            mB[c] = __builtin_elementwise_max(pmB[c], shfl2(pmB[c], lane + 1));
        }
        wave_sync();   // p1 reads drained before overwriting head with p2
        if (r < 5) {
            const int oc0 = ocp * 2;
            #pragma unroll
            for (int c = 0; c < 5; ++c) {
                p2A[oc0 * 25 + r * 5 + c]       = mA[c].x;
                p2A[(oc0 + 1) * 25 + r * 5 + c] = mA[c].y;
                p2B[oc0 * 25 + r * 5 + c]       = mB[c].x;
                p2B[(oc0 + 1) * 25 + r * 5 + c] = mB[c].y;
            }
        }
    }
    __syncthreads();   // all 8 images' p2 ready; weight region becomes scratch

    // ---- fc1 (120x400) K-split x2: 240 threads, 8 images per thread ----
    float* scr = lds;   // [8][240] = 1920 floats over dead weight region
    if (tid < 240) {
        const int row  = tid >> 1;
        const int half = tid & 1;
        const float4* wrow = (const float4*)(fc1w + row * 400) + half * 50;
        v2f acc[8];
        #pragma unroll
        for (int im = 0; im < 8; ++im) acc[im] = zero2;
        #pragma unroll 2
        for (int k = 0; k < 50; ++k) {
            float4 w4 = wrow[k];
            const v2f wxy = mk2(w4.x, w4.y), wzw = mk2(w4.z, w4.w);
            #pragma unroll
            for (int im = 0; im < 8; ++im) {
                const float4* ap = (const float4*)(lds + IMG_BASE + im * IMG_STRIDE + P2_OFF) + half * 50;
                float4 a = ap[k];
                acc[im] = __builtin_elementwise_fma(mk2(a.x, a.y), wxy, acc[im]);
                acc[im] = __builtin_elementwise_fma(mk2(a.z, a.w), wzw, acc[im]);
            }
        }
        #pragma unroll
        for (int im = 0; im < 8; ++im)
            scr[im * 240 + row * 2 + half] = acc[im].x + acc[im].y;
    }
    __syncthreads();

    // ---- fc1 reduce + bias + relu -> f1 per image (overwrites dead p2 head) ----
    if (tid < 120) {
        const float b = fc1b[tid];
        #pragma unroll
        for (int im = 0; im < 8; ++im) {
            float v = scr[im * 240 + tid * 2] + scr[im * 240 + tid * 2 + 1] + b;
            lds[IMG_BASE + im * IMG_STRIDE + F1_OFF + tid] = fmaxf(v, 0.f);
        }
    }
    __syncthreads();

    // ---- fc2 (84x120) + relu, 8 images per thread ----
    if (tid < 84) {
        const int row = tid;
        const float4* wrow = (const float4*)(fc2w + row * 120);
        const float bz = fc2b[row];
        v2f acc[8];
        #pragma unroll
        for (int im = 0; im < 8; ++im) acc[im] = zero2;
        #pragma unroll 2
        for (int k = 0; k < 30; ++k) {
            float4 w4 = wrow[k];
            const v2f wxy = mk2(w4.x, w4.y), wzw = mk2(w4.z, w4.w);
            #pragma unroll
            for (int im = 0; im < 8; ++im) {
                const float4* fp = (const float4*)(lds + IMG_BASE + im * IMG_STRIDE + F1_OFF);
                float4 a = fp[k];
                acc[im] = __builtin_elementwise_fma(mk2(a.x, a.y), wxy, acc[im]);
                acc[im] = __builtin_elementwise_fma(mk2(a.z, a.w), wzw, acc[im]);
            }
        }
        #pragma unroll
        for (int im = 0; im < 8; ++im)
            lds[IMG_BASE + im * IMG_STRIDE + F2_OFF + row] =
                fmaxf(acc[im].x + acc[im].y + bz, 0.f);
    }
    __syncthreads();

    // ---- fc3 (10x84) -> out, 8 images x 10 rows = 80 threads ----
    if (tid < 80) {
        const int im  = tid / 10;
        const int row = tid - im * 10;
        const float4* wrow = (const float4*)(fc3w + row * 84);
        const float4* f2 = (const float4*)(lds + IMG_BASE + im * IMG_STRIDE + F2_OFF);
        v2f acc = zero2;
        #pragma unroll
        for (int k = 0; k < 21; ++k) {
            float4 w4 = wrow[k];
            float4 a = f2[k];
            acc = __builtin_elementwise_fma(mk2(a.x, a.y), mk2(w4.x, w4.y), acc);
            acc = __builtin_elementwise_fma(mk2(a.z, a.w), mk2(w4.z, w4.w), acc);
        }
        out[(size_t)(img0 + im) * 10 + row] = acc.x + acc.y + fc3b[row];
    }
}

extern "C" void kernel_launch(void* const* d_in, const int* in_sizes, int n_in,
                              void* d_out, int out_size, void* d_ws, size_t ws_size,
                              hipStream_t stream) {
    const float* x    = (const float*)d_in[0];
    const float* w1   = (const float*)d_in[1];
    const float* w2   = (const float*)d_in[2];
    const float* fc1w = (const float*)d_in[3];
    const float* fc1b = (const float*)d_in[4];
    const float* fc2w = (const float*)d_in[5];
    const float* fc2b = (const float*)d_in[6];
    const float* fc3w = (const float*)d_in[7];
    const float* fc3b = (const float*)d_in[8];
    float* out = (float*)d_out;

    const int B = in_sizes[0] / 3072;       // 8192
    const int grid = B / IPB;               // 1024
    lenet_fused<<<grid, THREADS, 0, stream>>>(x, w1, w2, fc1w, fc1b,
                                              fc2w, fc2b, fc3w, fc3b, out);
}

// Round 2
// 208.781 us; speedup vs baseline: 1.0549x; 1.0270x over previous
//
#include <hip/hip_runtime.h>

// ---------------------------------------------------------------------------
// Fused LeNet forward, round 10: 1 image/wave + conflict-free xs rows.
//  - Round-9 counters: dur 89.5us, VALUBusy 43.7%, Occupancy 35.6%,
//    LDS conflicts 2.79M (5x regression from 16-float xs rows: 64B row
//    stride -> rows r, r+2 same banks -> 6-way conflict on conv1 b128).
//  - Fix 1: xs rows padded to 20 floats (80B): bank offset 20/row ->
//    collisions only at dr=8 (2-way = free, m136). Stage 16 cols, pad 4.
//  - Fix 2: structural TLP ceiling. 2 img/wave = 16 waves/CU max (4/SIMD)
//    cannot hide LDS latency + lgkmcnt drains. Go 1 img/wave: 512-thread
//    blocks, 8 waves, IPB=8, grid 1024 = 4 blocks/CU, LDS 40208B -> 4
//    blocks still fit (4x40960 = exactly 160KB). 32 waves/CU needs
//    VGPR<=64: launch_bounds(512,8). Single-image conv needs ~56 regs
//    (ILP-2 version fit 64 with ~2x the live state) -> no spill expected.
//  - fc: fc1 480 thr (row x Khalf x imh, 4 img each), fc2 168 thr.
// ---------------------------------------------------------------------------

typedef float v2f __attribute__((ext_vector_type(2)));
__device__ __forceinline__ v2f mk2(float a, float b) { v2f t; t.x = a; t.y = b; return t; }
__device__ __forceinline__ v2f shfl2(v2f v, int src) {
    v2f r; r.x = __shfl(v.x, src, 64); r.y = __shfl(v.y, src, 64); return r;
}

constexpr int THREADS = 512;
constexpr int IPB = 8;                 // images per block (1 per wave)

// LDS layout (float offsets)
constexpr int W1P_OFF = 0;             // conv1 w packed [ocp0..2][k0..74][2] = 450
constexpr int W2P_OFF = 452;           // conv2 w packed [ocp0..7][k0..149][2] = 2400
constexpr int IMG_BASE = 2852;
// per-image offsets (region reused phase to phase):
constexpr int XS_OFF = 0;              // [3][15] rows of 20 fl (16 used) = 900
constexpr int P1_OFF = 0;              // [6][10][12] = 720 (overwrites xs)
constexpr int P2_OFF = 0;              // [400] (overwrites p1 head; wave-local dep)
constexpr int F1_OFF = 0;              // [120]
constexpr int F2_OFF = 128;            // [84]
constexpr int IMG_STRIDE = 900;
constexpr int LDS_FLOATS = IMG_BASE + IPB * IMG_STRIDE;   // 10052 -> 40208 B

__device__ __forceinline__ void wave_sync() {
    asm volatile("s_waitcnt lgkmcnt(0)" ::: "memory");
}

extern "C" __global__ __launch_bounds__(THREADS, 8)
void lenet_fused(const float* __restrict__ x,
                 const float* __restrict__ w1,
                 const float* __restrict__ w2,
                 const float* __restrict__ fc1w, const float* __restrict__ fc1b,
                 const float* __restrict__ fc2w, const float* __restrict__ fc2b,
                 const float* __restrict__ fc3w, const float* __restrict__ fc3b,
                 float* __restrict__ out)
{
    __shared__ __align__(16) float lds[LDS_FLOATS];
    const int tid  = threadIdx.x;
    const int lane = tid & 63;
    const int wv   = tid >> 6;          // 0..7, owns image wv
    const int img0 = blockIdx.x * IPB;
    const v2f zero2 = mk2(0.f, 0.f);

    // ---- stage weights, repacked oc-pair-minor (block-wide) ----
    for (int i = tid; i < 450; i += THREADS) {
        int ocp = i / 150, rem = i - ocp * 150, k = rem >> 1, h = rem & 1;
        lds[W1P_OFF + i] = w1[(2 * ocp + h) * 75 + k];
    }
    for (int i = tid; i < 2400; i += THREADS) {
        int ocp = i / 300, rem = i - ocp * 300, k = rem >> 1, h = rem & 1;
        lds[W2P_OFF + i] = w2[(2 * ocp + h) * 150 + k];
    }

    // ---- stage input patch rows 0..14, cols 0..15 into 20-fl rows ----
    float* base = lds + IMG_BASE + wv * IMG_STRIDE;
    {
        const float4* xg = (const float4*)(x + (size_t)(img0 + wv) * 3072);
        float4* d = (float4*)(base + XS_OFF);
        for (int i = lane; i < 180; i += 64) {       // 3ch * 15r * 4(f4)
            int c = i / 60, rem = i - c * 60;
            int r = rem >> 2, c4 = rem & 3;
            d[c * 75 + r * 5 + c4] = xg[c * 256 + r * 8 + c4];   // 20-fl row pitch
        }
    }
    __syncthreads();   // weights + staging visible

    float* p1 = base + P1_OFF;

    // ---- conv1 + relu + pool1 -> p1 [6][10][12] ----
    // lane -> (ocp 0..2, r 0..10); 33 active, dup lanes guarded at store.
    {
        const int l   = (lane < 33) ? lane : 32;
        const int ocp = l / 11;
        const int r   = l - ocp * 11;
        const float4* xs = (const float4*)(base + XS_OFF);
        const v2f* w1p = (const v2f*)(lds + W1P_OFF);

        v2f acc[11];
        #pragma unroll
        for (int c = 0; c < 11; ++c) acc[c] = zero2;

        #pragma unroll
        for (int i = 0; i < 15; ++i) {
            const int ci = i / 5, kr = i - ci * 5;
            const int b = ci * 75 + (r + kr) * 5;    // 20-fl rows: 5 f4 pitch
            float4 A0 = xs[b], A1 = xs[b + 1], A2 = xs[b + 2], A3 = xs[b + 3];
            v2f W[5];
            #pragma unroll
            for (int kc = 0; kc < 5; ++kc) W[kc] = w1p[ocp * 75 + i * 5 + kc];
            float xa[16];
            xa[0]=A0.x; xa[1]=A0.y; xa[2]=A0.z;  xa[3]=A0.w;
            xa[4]=A1.x; xa[5]=A1.y; xa[6]=A1.z;  xa[7]=A1.w;
            xa[8]=A2.x; xa[9]=A2.y; xa[10]=A2.z; xa[11]=A2.w;
            xa[12]=A3.x; xa[13]=A3.y; xa[14]=A3.z; xa[15]=A3.w;
            #pragma unroll
            for (int kc = 0; kc < 5; ++kc) {
                #pragma unroll
                for (int c = 0; c < 11; ++c) {
                    acc[c] = __builtin_elementwise_fma(
                        mk2(xa[c + kc], xa[c + kc]), W[kc], acc[c]);
                }
            }
        }

        // relu + 2x2 stride-1 pool (packed over oc pair)
        v2f pm[10], m[10];
        #pragma unroll
        for (int c = 0; c < 10; ++c) {
            v2f a0 = __builtin_elementwise_max(acc[c], zero2);
            v2f a1 = __builtin_elementwise_max(acc[c + 1], zero2);
            pm[c] = __builtin_elementwise_max(a0, a1);
        }
        #pragma unroll
        for (int c = 0; c < 10; ++c)
            m[c] = __builtin_elementwise_max(pm[c], shfl2(pm[c], lane + 1));
        wave_sync();   // xs reads drained before overwriting region with p1
        if (r < 10) {
            const int oc0 = ocp * 2;
            float2* d0 = (float2*)(p1 + oc0 * 120 + r * 12);
            float2* d1 = (float2*)(p1 + (oc0 + 1) * 120 + r * 12);
            #pragma unroll
            for (int j = 0; j < 5; ++j) {
                d0[j] = make_float2(m[2 * j].x, m[2 * j + 1].x);
                d1[j] = make_float2(m[2 * j].y, m[2 * j + 1].y);
            }
        }
    }
    wave_sync();

    // ---- conv2 + relu + pool2 -> p2 [16*5*5] flatten order ----
    float* p2 = base + P2_OFF;
    {
        const int l   = (lane < 48) ? lane : 47;
        const int ocp = l / 6;
        const int r   = l - ocp * 6;
        const float4* pa4 = (const float4*)p1;
        const float2* pa2 = (const float2*)p1;
        const v2f* w2p = (const v2f*)(lds + W2P_OFF);

        v2f acc[6];
        #pragma unroll
        for (int c = 0; c < 6; ++c) acc[c] = zero2;

        #pragma unroll
        for (int i = 0; i < 30; ++i) {
            const int ci = i / 5, kr = i - ci * 5;
            float4 A0 = pa4[ci * 30 + (r + kr) * 3 + 0];
            float4 A1 = pa4[ci * 30 + (r + kr) * 3 + 1];
            float2 A2 = pa2[ci * 60 + (r + kr) * 6 + 4];
            v2f W[5];
            #pragma unroll
            for (int kc = 0; kc < 5; ++kc) W[kc] = w2p[ocp * 150 + i * 5 + kc];
            float xa[10];
            xa[0]=A0.x; xa[1]=A0.y; xa[2]=A0.z; xa[3]=A0.w;
            xa[4]=A1.x; xa[5]=A1.y; xa[6]=A1.z; xa[7]=A1.w;
            xa[8]=A2.x; xa[9]=A2.y;
            #pragma unroll
            for (int kc = 0; kc < 5; ++kc) {
                #pragma unroll
                for (int c = 0; c < 6; ++c) {
                    acc[c] = __builtin_elementwise_fma(
                        mk2(xa[c + kc], xa[c + kc]), W[kc], acc[c]);
                }
            }
        }

        v2f pm[5], m[5];
        #pragma unroll
        for (int c = 0; c < 5; ++c) {
            v2f a0 = __builtin_elementwise_max(acc[c], zero2);
            v2f a1 = __builtin_elementwise_max(acc[c + 1], zero2);
            pm[c] = __builtin_elementwise_max(a0, a1);
        }
        #pragma unroll
        for (int c = 0; c < 5; ++c)
            m[c] = __builtin_elementwise_max(pm[c], shfl2(pm[c], lane + 1));
        wave_sync();   // p1 reads drained before overwriting head with p2
        if (r < 5) {
            const int oc0 = ocp * 2;
            #pragma unroll
            for (int c = 0; c < 5; ++c) {
                p2[oc0 * 25 + r * 5 + c]       = m[c].x;
                p2[(oc0 + 1) * 25 + r * 5 + c] = m[c].y;
            }
        }
    }
    __syncthreads();   // all 8 images' p2 ready; weight region becomes scratch

    // ---- fc1 (120x400) 480 thr: (row, Khalf, imh), 4 images per thread ----
    float* scr = lds;   // [8][240] = 1920 floats over dead weight region
    if (tid < 480) {
        const int row  = tid >> 2;
        const int rh   = tid & 3;
        const int half = rh >> 1;
        const int imh  = rh & 1;       // images imh*4 .. imh*4+3
        const float4* wrow = (const float4*)(fc1w + row * 400) + half * 50;
        v2f acc[4];
        #pragma unroll
        for (int q = 0; q < 4; ++q) acc[q] = zero2;
        #pragma unroll 2
        for (int k = 0; k < 50; ++k) {
            float4 w4 = wrow[k];
            const v2f wxy = mk2(w4.x, w4.y), wzw = mk2(w4.z, w4.w);
            #pragma unroll
            for (int q = 0; q < 4; ++q) {
                const float4* ap = (const float4*)(lds + IMG_BASE + (imh * 4 + q) * IMG_STRIDE + P2_OFF) + half * 50;
                float4 a = ap[k];
                acc[q] = __builtin_elementwise_fma(mk2(a.x, a.y), wxy, acc[q]);
                acc[q] = __builtin_elementwise_fma(mk2(a.z, a.w), wzw, acc[q]);
            }
        }
        #pragma unroll
        for (int q = 0; q < 4; ++q)
            scr[(imh * 4 + q) * 240 + row * 2 + half] = acc[q].x + acc[q].y;
    }
    __syncthreads();

    // ---- fc1 reduce + bias + relu -> f1 per image ----
    if (tid < 120) {
        const float b = fc1b[tid];
        #pragma unroll
        for (int im = 0; im < 8; ++im) {
            float v = scr[im * 240 + tid * 2] + scr[im * 240 + tid * 2 + 1] + b;
            lds[IMG_BASE + im * IMG_STRIDE + F1_OFF + tid] = fmaxf(v, 0.f);
        }
    }
    __syncthreads();

    // ---- fc2 (84x120) + relu, 168 thr: (row, imh), 4 images per thread ----
    if (tid < 168) {
        const int row = tid >> 1;
        const int imh = tid & 1;
        const float4* wrow = (const float4*)(fc2w + row * 120);
        const float bz = fc2b[row];
        v2f acc[4];
        #pragma unroll
        for (int q = 0; q < 4; ++q) acc[q] = zero2;
        #pragma unroll 2
        for (int k = 0; k < 30; ++k) {
            float4 w4 = wrow[k];
            const v2f wxy = mk2(w4.x, w4.y), wzw = mk2(w4.z, w4.w);
            #pragma unroll
            for (int q = 0; q < 4; ++q) {
                const float4* fp = (const float4*)(lds + IMG_BASE + (imh * 4 + q) * IMG_STRIDE + F1_OFF);
                float4 a = fp[k];
                acc[q] = __builtin_elementwise_fma(mk2(a.x, a.y), wxy, acc[q]);
                acc[q] = __builtin_elementwise_fma(mk2(a.z, a.w), wzw, acc[q]);
            }
        }
        #pragma unroll
        for (int q = 0; q < 4; ++q)
            lds[IMG_BASE + (imh * 4 + q) * IMG_STRIDE + F2_OFF + row] =
                fmaxf(acc[q].x + acc[q].y + bz, 0.f);
    }
    __syncthreads();

    // ---- fc3 (10x84) -> out, 8 images x 10 rows = 80 threads ----
    if (tid < 80) {
        const int im  = tid / 10;
        const int row = tid - im * 10;
        const float4* wrow = (const float4*)(fc3w + row * 84);
        const float4* f2 = (const float4*)(lds + IMG_BASE + im * IMG_STRIDE + F2_OFF);
        v2f acc = zero2;
        #pragma unroll
        for (int k = 0; k < 21; ++k) {
            float4 w4 = wrow[k];
            float4 a = f2[k];
            acc = __builtin_elementwise_fma(mk2(a.x, a.y), mk2(w4.x, w4.y), acc);
            acc = __builtin_elementwise_fma(mk2(a.z, a.w), mk2(w4.z, w4.w), acc);
        }
        out[(size_t)(img0 + im) * 10 + row] = acc.x + acc.y + fc3b[row];
    }
}

extern "C" void kernel_launch(void* const* d_in, const int* in_sizes, int n_in,
                              void* d_out, int out_size, void* d_ws, size_t ws_size,
                              hipStream_t stream) {
    const float* x    = (const float*)d_in[0];
    const float* w1   = (const float*)d_in[1];
    const float* w2   = (const float*)d_in[2];
    const float* fc1w = (const float*)d_in[3];
    const float* fc1b = (const float*)d_in[4];
    const float* fc2w = (const float*)d_in[5];
    const float* fc2b = (const float*)d_in[6];
    const float* fc3w = (const float*)d_in[7];
    const float* fc3b = (const float*)d_in[8];
    float* out = (float*)d_out;

    const int B = in_sizes[0] / 3072;       // 8192
    const int grid = B / IPB;               // 1024
    lenet_fused<<<grid, THREADS, 0, stream>>>(x, w1, w2, fc1w, fc1b,
                                              fc2w, fc2b, fc3w, fc3b, out);
}